// Round 9
// baseline (507.773 us; speedup 1.0000x reference)
//
#include <hip/hip_runtime.h>
#include <cstddef>

constexpr int H  = 512;   // hidden
constexpr int F  = 21;    // features
constexpr int T  = 28;    // output steps
constexpr int NB = 192;   // 3 layer-groups x 64 blocks (<=256 CUs co-resident)
constexpr int NT = 256;   // 4 waves/block; 8 rows/block, 2 rows/wave
constexpr int NW = NT / 64;

#define SCOPE_AGENT __HIP_MEMORY_SCOPE_AGENT

// Tagged cross-block state: (tag<<32)|float_bits. Publish = RMW exchange
// (immediate at coherence point). Tag = producing decoder step t' + 2
// (encoder-produced state: tag 1). Slot parity: buf[t'&1].
__device__ unsigned long long g_hp[2][3][H];
__device__ unsigned g_exit;

struct P {
  const float *x, *py, *eW0, *eW1, *eW2, *ebih, *ebhh;
  const float *dW0, *dW1, *dW2, *dWhh, *dbih, *dbhh, *outW, *outb;
  float* out;
};

__device__ __forceinline__ float sigm(float v)  { return 1.0f / (1.0f + __expf(-v)); }
__device__ __forceinline__ float tanh_f(float v){ return 1.0f - 2.0f / (__expf(2.0f * v) + 1.0f); }

__device__ __forceinline__ float4 wredsum4(float4 v) {
#pragma unroll
  for (int off = 32; off > 0; off >>= 1) {
    v.x += __shfl_xor(v.x, off, 64);
    v.y += __shfl_xor(v.y, off, 64);
    v.z += __shfl_xor(v.z, off, 64);
    v.w += __shfl_xor(v.w, off, 64);
  }
  return v;
}
__device__ __forceinline__ float wredsum1(float v) {
#pragma unroll
  for (int off = 32; off > 0; off >>= 1) v += __shfl_xor(v, off, 64);
  return v;
}

__device__ __forceinline__ void pput(unsigned long long* slot, float v, unsigned tag) {
  union { float f; unsigned u; } c; c.f = v;
  unsigned long long pk = ((unsigned long long)tag << 32) | (unsigned long long)c.u;
  (void)__hip_atomic_exchange(slot, pk, __ATOMIC_RELAXED, SCOPE_AGENT);
}
__device__ __forceinline__ unsigned long long tld(const unsigned long long* q) {
  return __hip_atomic_load(q, __ATOMIC_RELAXED, SCOPE_AGENT);
}
__device__ __forceinline__ float fbits(unsigned long long v) {
  union { unsigned u; float f; } c; c.u = (unsigned)v; return c.f;
}

// Cooperative staged poll -> LDS; thread i owns elements {i, i+NT}; coalesced;
// single trailing barrier.
__device__ __forceinline__ void stagev(const unsigned long long* __restrict__ A,
                                       unsigned wa, float* __restrict__ dst) {
  const int i = threadIdx.x;
  unsigned long long v0 = tld(A + i), v1 = tld(A + i + NT);
  int guard = 0;
  while ((((unsigned)(v0 >> 32)) != wa || ((unsigned)(v1 >> 32)) != wa) &&
         ++guard < (1 << 20)) {
    v0 = tld(A + i); v1 = tld(A + i + NT);
  }
  dst[i] = fbits(v0); dst[i + NT] = fbits(v1);
  __syncthreads();
}

// One-off register poll (final y only).
__device__ __forceinline__ void pollvec8(const unsigned long long* __restrict__ A,
                                         int lane, unsigned want, float4& x0, float4& x1) {
  const unsigned long long* q = A + lane * 8;
  unsigned long long v[8];
#pragma unroll
  for (int k = 0; k < 8; ++k) v[k] = tld(q + k);
  int guard = 0;
  for (;;) {
    bool ok = true;
#pragma unroll
    for (int k = 0; k < 8; ++k) ok &= ((unsigned)(v[k] >> 32) == want);
    if (ok || ++guard > (1 << 20)) break;
#pragma unroll
    for (int k = 0; k < 8; ++k) v[k] = tld(q + k);
  }
  x0 = make_float4(fbits(v[0]), fbits(v[1]), fbits(v[2]), fbits(v[3]));
  x1 = make_float4(fbits(v[4]), fbits(v[5]), fbits(v[6]), fbits(v[7]));
}

// 4-gate weight fragment for one row (global), 64B/lane.
struct W8 { float4 a[4]; float4 b[4]; };
__device__ __forceinline__ W8 ldw_g(const float* __restrict__ W, int r, int lane) {
  W8 o;
#pragma unroll
  for (int g = 0; g < 4; ++g) {
    const float* q = W + (size_t)(g * H + r) * H + lane * 8;
    o.a[g] = *(const float4*)q;
    o.b[g] = *(const float4*)(q + 4);
  }
  return o;
}
__device__ __forceinline__ void fma8(const W8& wt, const float4& x0, const float4& x1,
                                     float s[4]) {
#pragma unroll
  for (int g = 0; g < 4; ++g) {
    s[g] += wt.a[g].x * x0.x + wt.a[g].y * x0.y + wt.a[g].z * x0.z + wt.a[g].w * x0.w
          + wt.b[g].x * x1.x + wt.b[g].y * x1.y + wt.b[g].z * x1.z + wt.b[g].w * x1.w;
  }
}

// Critical dot: 2 rows x 4 gates, weights in LDS [(i*4+g)*H + k], input in LDS.
__device__ __forceinline__ void dot2_lds(const float* __restrict__ wc, int i0, int lane,
                                         const float* __restrict__ xb, float s[2][4]) {
  float4 x0 = *(const float4*)(xb + lane * 8);
  float4 x1 = *(const float4*)(xb + lane * 8 + 4);
#pragma unroll
  for (int j = 0; j < 2; ++j)
#pragma unroll
    for (int g = 0; g < 4; ++g) {
      const float* q = wc + (size_t)((i0 + j) * 4 + g) * H + lane * 8;
      float4 a = *(const float4*)q;
      float4 b = *(const float4*)(q + 4);
      s[j][g] += a.x * x0.x + a.y * x0.y + a.z * x0.z + a.w * x0.w
               + b.x * x1.x + b.y * x1.y + b.z * x1.z + b.w * x1.w;
    }
}

__device__ __forceinline__ float cellup(const float4& v, const float b[4], float& c) {
  float cn = sigm(v.y + b[1]) * c + sigm(v.x + b[0]) * tanh_f(v.z + b[2]);
  c = cn;
  return sigm(v.w + b[3]) * tanh_f(cn);
}

__device__ __forceinline__ void write_y_frag(const P& p, int trow, int w, int lane,
                                             const float4& h0, const float4& h1,
                                             const float* sYe) {
  for (int j = w; j < F; j += NW) {
    const float* q = p.outW + (size_t)j * (2 * H) + lane * 8;
    float4 w0 = *(const float4*)q;
    float4 w1 = *(const float4*)(q + 4);
    float s = w0.x * h0.x + w0.y * h0.y + w0.z * h0.z + w0.w * h0.w
            + w1.x * h1.x + w1.y * h1.y + w1.z * h1.z + w1.w * h1.w;
    s = wredsum1(s);
    if (lane == 0) p.out[trow * F + j] = s + sYe[j];
  }
}

__global__ __launch_bounds__(NT, 1)
void k_flow(P p) {
  const int lane = threadIdx.x & 63;
  const int w    = threadIdx.x >> 6;
  const int gid  = blockIdx.x >> 6;   // layer group 0..2
  const int bq   = blockIdx.x & 63;   // block within group
  const int i0   = w * 2;             // row-in-block base (2 rows/wave)
  const int rb   = bq * 8;            // first row of this block
  const int r0   = rb + i0;           // rows r0, r0+1

  __shared__ float wcrit[8 * 4 * H];  // 64 KB: critical weight rows (M / dW1 / dW2)
  __shared__ float sBuf[2][H];        // staged fresh vectors (ping-pong per step)
  __shared__ float sAux[H];           // stale self-stage (sOld input)
  __shared__ float senc[H];           // group0: encoder output
  __shared__ float sYe[F + 3];        // group0: y_e = outW_e@enc + outb
  __shared__ int   s_last;

  float c[2] = {0.f, 0.f};
  float sOld[2][4] = {{0, 0, 0, 0}, {0, 0, 0, 0}};
  float bb[2][4];                     // steady-state per-row gate bias

  if (gid == 0) {
    // =================== GROUP 0: layer 0 (+ y output) ===================
    // ---- enc0: h=c=0 -> only eW0@x + biases. Publish tag 1. ----
    {
      float s[2][4] = {{0, 0, 0, 0}, {0, 0, 0, 0}};
      if (lane < F) {
        const float xv = p.x[lane];
#pragma unroll
        for (int j = 0; j < 2; ++j)
#pragma unroll
          for (int g = 0; g < 4; ++g)
            s[j][g] = p.eW0[(size_t)(g * H + r0 + j) * F + lane] * xv;
      }
      float4 v0 = wredsum4(make_float4(s[0][0], s[0][1], s[0][2], s[0][3]));
      float4 v1 = wredsum4(make_float4(s[1][0], s[1][1], s[1][2], s[1][3]));
      if (lane == 0) {
#pragma unroll
        for (int j = 0; j < 2; ++j) {
          const int r = r0 + j;
          float be[4];
#pragma unroll
          for (int g = 0; g < 4; ++g) be[g] = p.ebih[g * H + r] + p.ebhh[g * H + r];
          float4 v = j ? v1 : v0;
          pput(&g_hp[1][0][r], cellup(v, be, c[j]), 1u);
        }
      }
    }

    // ---- Build M rows into wcrit (input-independent; hides in enc1/enc2) ----
    {
      float4 mA[2][4], mB[2][4];
#pragma unroll
      for (int j = 0; j < 2; ++j)
#pragma unroll
        for (int g = 0; g < 4; ++g) {
          mA[j][g] = make_float4(0, 0, 0, 0);
          mB[j][g] = make_float4(0, 0, 0, 0);
        }
      for (int f = 0; f < F; ++f) {
        const float* q = p.outW + (size_t)f * (2 * H) + lane * 8;
        const float4 oa = *(const float4*)q;
        const float4 ob = *(const float4*)(q + 4);
#pragma unroll
        for (int j = 0; j < 2; ++j)
#pragma unroll
          for (int g = 0; g < 4; ++g) {
            const float wf = p.dW0[(size_t)(g * H + r0 + j) * (H + F) + f];
            mA[j][g].x += wf * oa.x; mA[j][g].y += wf * oa.y;
            mA[j][g].z += wf * oa.z; mA[j][g].w += wf * oa.w;
            mB[j][g].x += wf * ob.x; mB[j][g].y += wf * ob.y;
            mB[j][g].z += wf * ob.z; mB[j][g].w += wf * ob.w;
          }
      }
#pragma unroll
      for (int j = 0; j < 2; ++j)
#pragma unroll
        for (int g = 0; g < 4; ++g) {
          float* d = wcrit + (size_t)((i0 + j) * 4 + g) * H + lane * 8;
          *(float4*)d = mA[j][g];
          *(float4*)(d + 4) = mB[j][g];
        }
    }

    // ---- sOld0 init = Whh0 @ h0_enc (own rows; stale self-stage) ----
    {
      W8 wh0 = ldw_g(p.dWhh, r0, lane);
      W8 wh1 = ldw_g(p.dWhh, r0 + 1, lane);
      stagev(g_hp[1][0], 1u, sAux);
      float4 a0 = *(const float4*)(sAux + lane * 8);
      float4 a1 = *(const float4*)(sAux + lane * 8 + 4);
      fma8(wh0, a0, a1, sOld[0]);
      fma8(wh1, a0, a1, sOld[1]);
    }

    // ---- stage enc_out (hop 3) ----
    stagev(g_hp[1][2], 1u, senc);
    float4 e0 = *(const float4*)(senc + lane * 8);
    float4 e1 = *(const float4*)(senc + lane * 8 + 4);

    // encb = dW0_enc-part @ enc + biases (unaligned cols -> scalar)
    float encb[2][4];
    {
      float sg[2][4];
#pragma unroll
      for (int j = 0; j < 2; ++j)
#pragma unroll
        for (int g = 0; g < 4; ++g) {
          const float* q = p.dW0 + (size_t)(g * H + r0 + j) * (H + F) + F + lane * 8;
          sg[j][g] = q[0] * e0.x + q[1] * e0.y + q[2] * e0.z + q[3] * e0.w
                   + q[4] * e1.x + q[5] * e1.y + q[6] * e1.z + q[7] * e1.w;
        }
      float4 v0 = wredsum4(make_float4(sg[0][0], sg[0][1], sg[0][2], sg[0][3]));
      float4 v1 = wredsum4(make_float4(sg[1][0], sg[1][1], sg[1][2], sg[1][3]));
      const float vv0[4] = {v0.x, v0.y, v0.z, v0.w};
      const float vv1[4] = {v1.x, v1.y, v1.z, v1.w};
#pragma unroll
      for (int g = 0; g < 4; ++g) {
        encb[0][g] = vv0[g] + p.dbih[g * H + r0] + p.dbhh[g * H + r0];
        encb[1][g] = vv1[g] + p.dbih[g * H + r0 + 1] + p.dbhh[g * H + r0 + 1];
      }
    }

    // b00 = encb + dW0[:,:F]@prev_y ; publish h0(0) tag 2 (no M term at t=0)
    {
      float s[2][4] = {{0, 0, 0, 0}, {0, 0, 0, 0}};
      if (lane < F) {
        const float yv = p.py[lane];
#pragma unroll
        for (int j = 0; j < 2; ++j)
#pragma unroll
          for (int g = 0; g < 4; ++g)
            s[j][g] = p.dW0[(size_t)(g * H + r0 + j) * (H + F) + lane] * yv;
      }
      float4 v0 = wredsum4(make_float4(s[0][0], s[0][1], s[0][2], s[0][3]));
      float4 v1 = wredsum4(make_float4(s[1][0], s[1][1], s[1][2], s[1][3]));
      if (lane == 0) {
        const float pv0[4] = {v0.x, v0.y, v0.z, v0.w};
        const float pv1[4] = {v1.x, v1.y, v1.z, v1.w};
#pragma unroll
        for (int j = 0; j < 2; ++j) {
          float b00[4];
#pragma unroll
          for (int g = 0; g < 4; ++g)
            b00[g] = encb[j][g] + (j ? pv1[g] : pv0[g]);
          float4 v = make_float4(sOld[j][0], sOld[j][1], sOld[j][2], sOld[j][3]);
          pput(&g_hp[0][0][r0 + j], cellup(v, b00, c[j]), 2u);
        }
      }
    }

    // ---- idle-slack work: sYe, b0p fold, sOld0 for t=1 ----
    for (int j = w; j < F; j += NW) {  // y_e rows
      const float* q = p.outW + (size_t)j * (2 * H) + H + lane * 8;
      float4 w0 = *(const float4*)q;
      float4 w1 = *(const float4*)(q + 4);
      float s = w0.x * e0.x + w0.y * e0.y + w0.z * e0.z + w0.w * e0.w
              + w1.x * e1.x + w1.y * e1.y + w1.z * e1.z + w1.w * e1.w;
      s = wredsum1(s);
      if (lane == 0) sYe[j] = s + p.outb[j];
    }
    __syncthreads();
    {  // bb = encb + dW0[:,:F]@y_e  (t>=1 constant)
      float s[2][4] = {{0, 0, 0, 0}, {0, 0, 0, 0}};
      if (lane < F) {
        const float yv = sYe[lane];
#pragma unroll
        for (int j = 0; j < 2; ++j)
#pragma unroll
          for (int g = 0; g < 4; ++g)
            s[j][g] = p.dW0[(size_t)(g * H + r0 + j) * (H + F) + lane] * yv;
      }
      float4 v0 = wredsum4(make_float4(s[0][0], s[0][1], s[0][2], s[0][3]));
      float4 v1 = wredsum4(make_float4(s[1][0], s[1][1], s[1][2], s[1][3]));
      const float pv0[4] = {v0.x, v0.y, v0.z, v0.w};
      const float pv1[4] = {v1.x, v1.y, v1.z, v1.w};
#pragma unroll
      for (int g = 0; g < 4; ++g) {
        bb[0][g] = encb[0][g] + pv0[g];
        bb[1][g] = encb[1][g] + pv1[g];
      }
    }
    {  // sOld0 = Whh0 @ h0(0)
      W8 wh0 = ldw_g(p.dWhh, r0, lane);
      W8 wh1 = ldw_g(p.dWhh, r0 + 1, lane);
      __syncthreads();
      stagev(g_hp[0][0], 2u, sAux);
      float4 a0 = *(const float4*)(sAux + lane * 8);
      float4 a1 = *(const float4*)(sAux + lane * 8 + 4);
      sOld[0][0] = sOld[0][1] = sOld[0][2] = sOld[0][3] = 0.f;
      sOld[1][0] = sOld[1][1] = sOld[1][2] = sOld[1][3] = 0.f;
      fma8(wh0, a0, a1, sOld[0]);
      fma8(wh1, a0, a1, sOld[1]);
    }

    // ---- decoder t = 1..T-1: crit = M(LDS)@h2(t-1) + sOld0 + bb ----
    for (int t = 1; t < T; ++t) {
      float* xb = sBuf[t & 1];
      stagev(g_hp[(t - 1) & 1][2], (unsigned)(t + 1), xb);
      float s[2][4] = {{sOld[0][0], sOld[0][1], sOld[0][2], sOld[0][3]},
                       {sOld[1][0], sOld[1][1], sOld[1][2], sOld[1][3]}};
      dot2_lds(wcrit, i0, lane, xb, s);
      float4 v0 = wredsum4(make_float4(s[0][0], s[0][1], s[0][2], s[0][3]));
      float4 v1 = wredsum4(make_float4(s[1][0], s[1][1], s[1][2], s[1][3]));
      if (lane == 0) {
        pput(&g_hp[t & 1][0][r0],     cellup(v0, bb[0], c[0]), (unsigned)(t + 2));
        pput(&g_hp[t & 1][0][r0 + 1], cellup(v1, bb[1], c[1]), (unsigned)(t + 2));
      }
      // extras (2 phases of slack): y(t-1) by rotating block; sOld0 refresh
      if (bq == t) {
        float4 h20 = *(const float4*)(xb + lane * 8);
        float4 h21 = *(const float4*)(xb + lane * 8 + 4);
        write_y_frag(p, t - 1, w, lane, h20, h21, sYe);
      }
      W8 wh0 = ldw_g(p.dWhh, r0, lane);
      W8 wh1 = ldw_g(p.dWhh, r0 + 1, lane);
      __syncthreads();
      stagev(g_hp[t & 1][0], (unsigned)(t + 2), sAux);
      float4 a0 = *(const float4*)(sAux + lane * 8);
      float4 a1 = *(const float4*)(sAux + lane * 8 + 4);
      sOld[0][0] = sOld[0][1] = sOld[0][2] = sOld[0][3] = 0.f;
      sOld[1][0] = sOld[1][1] = sOld[1][2] = sOld[1][3] = 0.f;
      fma8(wh0, a0, a1, sOld[0]);
      fma8(wh1, a0, a1, sOld[1]);
    }

    // ---- final y(T-1): dedicated block ----
    if (bq == T) {
      float4 h20, h21;
      pollvec8(g_hp[(T - 1) & 1][2], lane, (unsigned)(T + 1), h20, h21);
      write_y_frag(p, T - 1, w, lane, h20, h21, sYe);
    }
  } else {
    // =================== GROUPS 1/2: layers 1/2 ===================
    const int l = gid;
    const float* Wih  = (l == 1) ? p.dW1 : p.dW2;
    const float* Whh  = p.dWhh + (size_t)l * 4 * H * H;
    const float* eW   = (l == 1) ? p.eW1 : p.eW2;
#pragma unroll
    for (int j = 0; j < 2; ++j)
#pragma unroll
      for (int g = 0; g < 4; ++g)
        bb[j][g] = p.dbih[l * 4 * H + g * H + r0 + j] + p.dbhh[l * 4 * H + g * H + r0 + j];

    // ---- encoder layer l: poll h_{l-1}_enc (tag 1), global weights ----
    {
      W8 we0 = ldw_g(eW, r0, lane);
      W8 we1 = ldw_g(eW, r0 + 1, lane);
      stagev(g_hp[1][l - 1], 1u, sBuf[0]);
      float4 a0 = *(const float4*)(sBuf[0] + lane * 8);
      float4 a1 = *(const float4*)(sBuf[0] + lane * 8 + 4);
      float s[2][4] = {{0, 0, 0, 0}, {0, 0, 0, 0}};
      fma8(we0, a0, a1, s[0]);
      fma8(we1, a0, a1, s[1]);
      float4 v0 = wredsum4(make_float4(s[0][0], s[0][1], s[0][2], s[0][3]));
      float4 v1 = wredsum4(make_float4(s[1][0], s[1][1], s[1][2], s[1][3]));
      if (lane == 0) {
#pragma unroll
        for (int j = 0; j < 2; ++j) {
          const int r = r0 + j;
          float be[4];
#pragma unroll
          for (int g = 0; g < 4; ++g)
            be[g] = p.ebih[l * 4 * H + g * H + r] + p.ebhh[l * 4 * H + g * H + r];
          float4 v = j ? v1 : v0;
          pput(&g_hp[1][l][r], cellup(v, be, c[j]), 1u);
        }
      }
    }

    // ---- setup in slack: wcrit <- Wih rows; sOld init = Whh @ h_l_enc ----
    for (int u = threadIdx.x; u < 8 * 4 * (H / 4); u += NT) {
      const int i   = u / (4 * (H / 4));
      const int rem = u - i * 4 * (H / 4);
      const int g   = rem / (H / 4);
      const int k4  = rem - g * (H / 4);
      const float4* src = (const float4*)(Wih + (size_t)(g * H + rb + i) * H) + k4;
      ((float4*)(wcrit + (size_t)(i * 4 + g) * H))[k4] = *src;
    }
    {
      W8 wh0 = ldw_g(Whh, r0, lane);
      W8 wh1 = ldw_g(Whh, r0 + 1, lane);
      stagev(g_hp[1][l], 1u, sAux);
      float4 a0 = *(const float4*)(sAux + lane * 8);
      float4 a1 = *(const float4*)(sAux + lane * 8 + 4);
      fma8(wh0, a0, a1, sOld[0]);
      fma8(wh1, a0, a1, sOld[1]);
    }
    __syncthreads();  // wcrit + sBuf[0] settled before decoder

    // ---- decoder t = 0..T-1: crit = Wih(LDS)@h_{l-1}(t) + sOld + bb ----
    for (int t = 0; t < T; ++t) {
      float* xb = sBuf[t & 1];
      stagev(g_hp[t & 1][l - 1], (unsigned)(t + 2), xb);
      float s[2][4] = {{sOld[0][0], sOld[0][1], sOld[0][2], sOld[0][3]},
                       {sOld[1][0], sOld[1][1], sOld[1][2], sOld[1][3]}};
      dot2_lds(wcrit, i0, lane, xb, s);
      float4 v0 = wredsum4(make_float4(s[0][0], s[0][1], s[0][2], s[0][3]));
      float4 v1 = wredsum4(make_float4(s[1][0], s[1][1], s[1][2], s[1][3]));
      if (lane == 0) {
        pput(&g_hp[t & 1][l][r0],     cellup(v0, bb[0], c[0]), (unsigned)(t + 2));
        pput(&g_hp[t & 1][l][r0 + 1], cellup(v1, bb[1], c[1]), (unsigned)(t + 2));
      }
      // extras: sOld refresh from own just-published vector (2 phases slack)
      W8 wh0 = ldw_g(Whh, r0, lane);
      W8 wh1 = ldw_g(Whh, r0 + 1, lane);
      __syncthreads();
      stagev(g_hp[t & 1][l], (unsigned)(t + 2), sAux);
      float4 a0 = *(const float4*)(sAux + lane * 8);
      float4 a1 = *(const float4*)(sAux + lane * 8 + 4);
      sOld[0][0] = sOld[0][1] = sOld[0][2] = sOld[0][3] = 0.f;
      sOld[1][0] = sOld[1][1] = sOld[1][2] = sOld[1][3] = 0.f;
      fma8(wh0, a0, a1, sOld[0]);
      fma8(wh1, a0, a1, sOld[1]);
    }
  }

  // ---- Exit: last block resets tags so graph replays start clean ----
  __syncthreads();
  if (threadIdx.x == 0) {
    unsigned old = __hip_atomic_fetch_add(&g_exit, 1u, __ATOMIC_RELAXED, SCOPE_AGENT);
    s_last = (old == NB - 1) ? 1 : 0;
  }
  __syncthreads();
  if (s_last) {
    unsigned long long* z = &g_hp[0][0][0];
    for (int i = threadIdx.x; i < 2 * 3 * H; i += NT)
      __hip_atomic_store(z + i, 0ull, __ATOMIC_RELAXED, SCOPE_AGENT);
    if (threadIdx.x == 0)
      __hip_atomic_store(&g_exit, 0u, __ATOMIC_RELAXED, SCOPE_AGENT);
  }
}

extern "C" void kernel_launch(void* const* d_in, const int* in_sizes, int n_in,
                              void* d_out, int out_size, void* d_ws, size_t ws_size,
                              hipStream_t stream) {
  P p;
  p.x    = (const float*)d_in[0];
  p.py   = (const float*)d_in[1];
  p.eW0  = (const float*)d_in[2];
  p.eW1  = (const float*)d_in[3];
  p.eW2  = (const float*)d_in[4];
  // d_in[5] enc_Whh: unused (encoder runs one step from h=0)
  p.ebih = (const float*)d_in[6];
  p.ebhh = (const float*)d_in[7];
  // d_in[8..10] attn_W/attn_b/v_W: unused (softmax over length-1 axis == 1)
  p.dW0  = (const float*)d_in[11];
  p.dW1  = (const float*)d_in[12];
  p.dW2  = (const float*)d_in[13];
  p.dWhh = (const float*)d_in[14];
  p.dbih = (const float*)d_in[15];
  p.dbhh = (const float*)d_in[16];
  p.outW = (const float*)d_in[17];
  p.outb = (const float*)d_in[18];
  p.out  = (float*)d_out;

  hipLaunchKernelGGL(k_flow, dim3(NB), dim3(NT), 0, stream, p);
}

// Round 10
// 317.427 us; speedup vs baseline: 1.5996x; 1.5996x over previous
//
#include <hip/hip_runtime.h>
#include <cstddef>

constexpr int H  = 512;   // hidden
constexpr int F  = 21;    // features
constexpr int T  = 28;    // output steps
constexpr int PB = 128;   // producer blocks (R8-best geometry)
constexpr int NB = PB + 1;// + 1 dedicated y-writer block
constexpr int NT = 256;   // 4 waves/block -> 512 producer waves, 1 row/wave
constexpr int NW = NT / 64;

#define SCOPE_AGENT __HIP_MEMORY_SCOPE_AGENT

// Tagged cross-block state: (tag<<32)|float_bits. Publish = RMW exchange
// (immediate at coherence point). Tag = producing decoder step t' + 2
// (encoder-produced state: tag 1). g_hy is step-unique (never overwritten
// within a call) so the y-writer can never lose a WAR race.
__device__ unsigned long long g_hp[2][3][H];
__device__ unsigned long long g_hy[T][H];
__device__ unsigned g_exit;

struct P {
  const float *x, *py, *eW0, *eW1, *eW2, *ebih, *ebhh;
  const float *dW0, *dW1, *dW2, *dWhh, *dbih, *dbhh, *outW, *outb;
  float* out;
};

__device__ __forceinline__ float sigm(float v)  { return 1.0f / (1.0f + __expf(-v)); }
__device__ __forceinline__ float tanh_f(float v){ return 1.0f - 2.0f / (__expf(2.0f * v) + 1.0f); }

__device__ __forceinline__ float4 wredsum4(float4 v) {
#pragma unroll
  for (int off = 32; off > 0; off >>= 1) {
    v.x += __shfl_xor(v.x, off, 64);
    v.y += __shfl_xor(v.y, off, 64);
    v.z += __shfl_xor(v.z, off, 64);
    v.w += __shfl_xor(v.w, off, 64);
  }
  return v;
}
__device__ __forceinline__ float wredsum1(float v) {
#pragma unroll
  for (int off = 32; off > 0; off >>= 1) v += __shfl_xor(v, off, 64);
  return v;
}

__device__ __forceinline__ void pput(unsigned long long* slot, float v, unsigned tag) {
  union { float f; unsigned u; } c; c.f = v;
  unsigned long long pk = ((unsigned long long)tag << 32) | (unsigned long long)c.u;
  (void)__hip_atomic_exchange(slot, pk, __ATOMIC_RELAXED, SCOPE_AGENT);
}
__device__ __forceinline__ unsigned long long tld(const unsigned long long* q) {
  return __hip_atomic_load(q, __ATOMIC_RELAXED, SCOPE_AGENT);
}
__device__ __forceinline__ float fbits(unsigned long long v) {
  union { unsigned u; float f; } c; c.u = (unsigned)v; return c.f;
}

// Cooperative staged poll -> LDS: thread i owns elements {i, i+NT}; coalesced;
// both loads in flight per attempt; single trailing barrier.
__device__ __forceinline__ void stagev(const unsigned long long* __restrict__ A,
                                       unsigned wa, float* __restrict__ dst) {
  const int i = threadIdx.x;
  unsigned long long v0 = tld(A + i), v1 = tld(A + i + NT);
  int guard = 0;
  while ((((unsigned)(v0 >> 32)) != wa || ((unsigned)(v1 >> 32)) != wa) &&
         ++guard < (1 << 20)) {
    v0 = tld(A + i); v1 = tld(A + i + NT);
  }
  dst[i] = fbits(v0); dst[i + NT] = fbits(v1);
  __syncthreads();
}

// 4-gate weight fragment block: 8 float4 = 64B/lane per matrix.
struct W8 { float4 a[4]; float4 b[4]; };

__device__ __forceinline__ W8 ldw_g(const float* __restrict__ W, int r, int lane) {
  W8 o;
#pragma unroll
  for (int g = 0; g < 4; ++g) {
    const float* q = W + (size_t)(g * H + r) * H + lane * 8;
    o.a[g] = *(const float4*)q;
    o.b[g] = *(const float4*)(q + 4);
  }
  return o;
}
__device__ __forceinline__ W8 ldw_lds(const float* sM, int w, int lane) {
  W8 o;
#pragma unroll
  for (int g = 0; g < 4; ++g) {
    const float* q = sM + (w * 4 + g) * H + lane * 8;
    o.a[g] = *(const float4*)q;
    o.b[g] = *(const float4*)(q + 4);
  }
  return o;
}
__device__ __forceinline__ void fma8(const W8& wt, const float4& x0, const float4& x1,
                                     float s[4]) {
#pragma unroll
  for (int g = 0; g < 4; ++g) {
    s[g] += wt.a[g].x * x0.x + wt.a[g].y * x0.y + wt.a[g].z * x0.z + wt.a[g].w * x0.w
          + wt.b[g].x * x1.x + wt.b[g].y * x1.y + wt.b[g].z * x1.z + wt.b[g].w * x1.w;
  }
}

__device__ __forceinline__ float cellup(const float4& v, const float b[4], float& c) {
  float cn = sigm(v.y + b[1]) * c + sigm(v.x + b[0]) * tanh_f(v.z + b[2]);
  c = cn;
  return sigm(v.w + b[3]) * tanh_f(cn);
}

__device__ __forceinline__ void write_y_frag(const P& p, int trow, int w, int lane,
                                             const float4& h0, const float4& h1,
                                             const float* sYe) {
  for (int j = w; j < F; j += NW) {
    const float* q = p.outW + (size_t)j * (2 * H) + lane * 8;
    float4 w0 = *(const float4*)q;
    float4 w1 = *(const float4*)(q + 4);
    float s = w0.x * h0.x + w0.y * h0.y + w0.z * h0.z + w0.w * h0.w
            + w1.x * h1.x + w1.y * h1.y + w1.z * h1.z + w1.w * h1.w;
    s = wredsum1(s);
    if (lane == 0) p.out[trow * F + j] = s + sYe[j];
  }
}

__global__ __launch_bounds__(NT, 1)
void k_flow(P p) {
  const int lane = threadIdx.x & 63;
  const int w    = threadIdx.x >> 6;

  __shared__ float sM[NW * 4 * H];   // 32 KB: producer rows of M = dW0[:,:F]@outW_h
  __shared__ float sBuf[2][H];       // 4 KB: double-buffered staged vector
  __shared__ float senc[H];          // persistent encoder output
  __shared__ float sYe[F + 3];       // y_e = outW_e@enc + outb
  __shared__ int   s_last;

  if (blockIdx.x == PB) {
    // ================= Dedicated y-writer block (off critical path) ========
    // Stage enc (tag 1) -> sYe; then consume step-unique g_hy slots.
    stagev(g_hp[1][2], 1u, senc);
    {
      float4 e0 = *(const float4*)(senc + lane * 8);
      float4 e1 = *(const float4*)(senc + lane * 8 + 4);
      for (int j = w; j < F; j += NW) {
        const float* q = p.outW + (size_t)j * (2 * H) + H + lane * 8;
        float4 w0 = *(const float4*)q;
        float4 w1 = *(const float4*)(q + 4);
        float s = w0.x * e0.x + w0.y * e0.y + w0.z * e0.z + w0.w * e0.w
                + w1.x * e1.x + w1.y * e1.y + w1.z * e1.z + w1.w * e1.w;
        s = wredsum1(s);
        if (lane == 0) sYe[j] = s + p.outb[j];
      }
      __syncthreads();
    }
    for (int t = 0; t < T; ++t) {
      float* xb = sBuf[t & 1];
      stagev(g_hy[t], (unsigned)(t + 2), xb);  // h2(t), step-unique slot
      float4 h20 = *(const float4*)(xb + lane * 8);
      float4 h21 = *(const float4*)(xb + lane * 8 + 4);
      write_y_frag(p, t, w, lane, h20, h21, sYe);
    }
  } else {
    // ========================= Producer blocks =============================
    const int r = blockIdx.x * NW + w;  // 1 row/wave, fixed mapping (L2 locality)

    float c0 = 0.f, c1 = 0.f, c2 = 0.f;
    float b00[4], b0p[4], b1s[4], b2s[4];  // lane-0-meaningful biases
    float sOld0[4] = {0, 0, 0, 0}, sOld1[4] = {0, 0, 0, 0}, sOld2[4] = {0, 0, 0, 0};
    int bi = 0;

    // ---- Encoder layer 0: h=c=0 -> Whh zero, f-gate dead. Publish tag 1. ----
    {
      float s0 = 0.f, s1 = 0.f, s2 = 0.f, s3 = 0.f;
      if (lane < F) {
        const float xv = p.x[lane];
        s0 = p.eW0[(size_t)(0 * H + r) * F + lane] * xv;
        s1 = p.eW0[(size_t)(1 * H + r) * F + lane] * xv;
        s2 = p.eW0[(size_t)(2 * H + r) * F + lane] * xv;
        s3 = p.eW0[(size_t)(3 * H + r) * F + lane] * xv;
      }
      float4 v = wredsum4(make_float4(s0, s1, s2, s3));
      if (lane == 0) {
        const float* bi_ = p.ebih + r;
        const float* bh_ = p.ebhh + r;
        float cn = sigm(v.x + bi_[0] + bh_[0]) * tanh_f(v.z + bi_[2 * H] + bh_[2 * H]);
        c0 = cn;
        pput(&g_hp[1][0][r], sigm(v.w + bi_[3 * H] + bh_[3 * H]) * tanh_f(cn), 1u);
      }
    }

    // ---- Build sM while other blocks finish enc0 (input-independent) ----
    {
      float4 mA[4], mB[4];
#pragma unroll
      for (int g = 0; g < 4; ++g) {
        mA[g] = make_float4(0.f, 0.f, 0.f, 0.f);
        mB[g] = make_float4(0.f, 0.f, 0.f, 0.f);
      }
      for (int f = 0; f < F; ++f) {
        const float* q = p.outW + (size_t)f * (2 * H) + lane * 8;
        const float4 oa = *(const float4*)q;
        const float4 ob = *(const float4*)(q + 4);
#pragma unroll
        for (int g = 0; g < 4; ++g) {
          const float wf = p.dW0[(size_t)(g * H + r) * (H + F) + f];
          mA[g].x += wf * oa.x; mA[g].y += wf * oa.y; mA[g].z += wf * oa.z; mA[g].w += wf * oa.w;
          mB[g].x += wf * ob.x; mB[g].y += wf * ob.y; mB[g].z += wf * ob.z; mB[g].w += wf * ob.w;
        }
      }
#pragma unroll
      for (int g = 0; g < 4; ++g) {
        *(float4*)(sM + (w * 4 + g) * H + lane * 8)     = mA[g];
        *(float4*)(sM + (w * 4 + g) * H + lane * 8 + 4) = mB[g];
      }
    }
#pragma unroll
    for (int g = 0; g < 4; ++g) {
      b1s[g] = p.dbih[4 * H + g * H + r] + p.dbhh[4 * H + g * H + r];
      b2s[g] = p.dbih[8 * H + g * H + r] + p.dbhh[8 * H + g * H + r];
    }

    // ---- Encoder layer 1 (stages h0_enc into sBuf[0]; kept for decoder t=0) ----
    {
      W8 wt = ldw_g(p.eW1, r, lane);  // prefetch before poll
      stagev(g_hp[1][0], 1u, sBuf[0]);
      float4 a0 = *(const float4*)(sBuf[0] + lane * 8);
      float4 a1 = *(const float4*)(sBuf[0] + lane * 8 + 4);
      float s[4] = {0.f, 0.f, 0.f, 0.f};
      fma8(wt, a0, a1, s);
      float4 v = wredsum4(make_float4(s[0], s[1], s[2], s[3]));
      if (lane == 0) {
        const float* bi_ = p.ebih + 4 * H + r;
        const float* bh_ = p.ebhh + 4 * H + r;
        float cn = sigm(v.x + bi_[0] + bh_[0]) * tanh_f(v.z + bi_[2 * H] + bh_[2 * H]);
        c1 = cn;
        pput(&g_hp[1][1][r], sigm(v.w + bi_[3 * H] + bh_[3 * H]) * tanh_f(cn), 1u);
      }
    }

    // ---- Encoder layer 2 -> enc_out; extra: sOld1 = Whh1@h1_enc (for S1(0)) ----
    {
      W8 wt  = ldw_g(p.eW2, r, lane);
      W8 wh1 = ldw_g(p.dWhh + (size_t)4 * H * H, r, lane);
      stagev(g_hp[1][1], 1u, sBuf[1]);
      float4 a0 = *(const float4*)(sBuf[1] + lane * 8);
      float4 a1 = *(const float4*)(sBuf[1] + lane * 8 + 4);
      float s[4] = {0.f, 0.f, 0.f, 0.f};
      fma8(wt, a0, a1, s);
      float4 v = wredsum4(make_float4(s[0], s[1], s[2], s[3]));
      if (lane == 0) {
        const float* bi_ = p.ebih + 8 * H + r;
        const float* bh_ = p.ebhh + 8 * H + r;
        float cn = sigm(v.x + bi_[0] + bh_[0]) * tanh_f(v.z + bi_[2 * H] + bh_[2 * H]);
        c2 = cn;
        pput(&g_hp[1][2][r], sigm(v.w + bi_[3 * H] + bh_[3 * H]) * tanh_f(cn), 1u);
      }
      fma8(wh1, a0, a1, sOld1);
    }

    // ---- Setup: senc, y_e, base0 constants; extra: sOld2 = Whh2@enc ----
    {
      W8 wh2 = ldw_g(p.dWhh + (size_t)8 * H * H, r, lane);
      stagev(g_hp[1][2], 1u, senc);   // senc persists (read-only afterwards)
      float4 e0 = *(const float4*)(senc + lane * 8);
      float4 e1 = *(const float4*)(senc + lane * 8 + 4);
      for (int j = w; j < F; j += NW) {  // y_e rows -> sYe (needed for b0p fold)
        const float* q = p.outW + (size_t)j * (2 * H) + H + lane * 8;
        float4 w0 = *(const float4*)q;
        float4 w1 = *(const float4*)(q + 4);
        float s = w0.x * e0.x + w0.y * e0.y + w0.z * e0.z + w0.w * e0.w
                + w1.x * e1.x + w1.y * e1.y + w1.z * e1.z + w1.w * e1.w;
        s = wredsum1(s);
        if (lane == 0) sYe[j] = s + p.outb[j];
      }
      {  // enc part of base0 (unaligned dW0 cols F..F+511 -> scalar)
        float sg[4];
#pragma unroll
        for (int g = 0; g < 4; ++g) {
          const float* q = p.dW0 + (size_t)(g * H + r) * (H + F) + F + lane * 8;
          sg[g] = q[0] * e0.x + q[1] * e0.y + q[2] * e0.z + q[3] * e0.w
                + q[4] * e1.x + q[5] * e1.y + q[6] * e1.z + q[7] * e1.w;
        }
        float4 v = wredsum4(make_float4(sg[0], sg[1], sg[2], sg[3]));
        if (lane == 0) {
          b0p[0] = v.x + p.dbih[0 * H + r] + p.dbhh[0 * H + r];
          b0p[1] = v.y + p.dbih[1 * H + r] + p.dbhh[1 * H + r];
          b0p[2] = v.z + p.dbih[2 * H + r] + p.dbhh[2 * H + r];
          b0p[3] = v.w + p.dbih[3 * H + r] + p.dbhh[3 * H + r];
        }
      }
      {  // prev_y part -> b00 (t=0 constant)
        float f0 = 0.f, f1 = 0.f, f2 = 0.f, f3 = 0.f;
        if (lane < F) {
          const float yv = p.py[lane];
          f0 = p.dW0[(size_t)(0 * H + r) * (H + F) + lane] * yv;
          f1 = p.dW0[(size_t)(1 * H + r) * (H + F) + lane] * yv;
          f2 = p.dW0[(size_t)(2 * H + r) * (H + F) + lane] * yv;
          f3 = p.dW0[(size_t)(3 * H + r) * (H + F) + lane] * yv;
        }
        float4 v = wredsum4(make_float4(f0, f1, f2, f3));
        if (lane == 0) {
          b00[0] = b0p[0] + v.x; b00[1] = b0p[1] + v.y;
          b00[2] = b0p[2] + v.z; b00[3] = b0p[3] + v.w;
        }
      }
      __syncthreads();  // sYe visible
      {  // fold dW0[:,:F] @ y_e into b0p (t>=1 constant)
        float f0 = 0.f, f1 = 0.f, f2 = 0.f, f3 = 0.f;
        if (lane < F) {
          const float yv = sYe[lane];
          f0 = p.dW0[(size_t)(0 * H + r) * (H + F) + lane] * yv;
          f1 = p.dW0[(size_t)(1 * H + r) * (H + F) + lane] * yv;
          f2 = p.dW0[(size_t)(2 * H + r) * (H + F) + lane] * yv;
          f3 = p.dW0[(size_t)(3 * H + r) * (H + F) + lane] * yv;
        }
        float4 v = wredsum4(make_float4(f0, f1, f2, f3));
        if (lane == 0) {
          b0p[0] += v.x; b0p[1] += v.y; b0p[2] += v.z; b0p[3] += v.w;
        }
      }
      fma8(wh2, e0, e1, sOld2);
    }

    // ---- Decoder t=0 S0: Whh0 @ h0_enc (still live in sBuf[0]) + b00. No poll. ----
    {
      W8 wh0 = ldw_g(p.dWhh, r, lane);
      float4 a0 = *(const float4*)(sBuf[0] + lane * 8);
      float4 a1 = *(const float4*)(sBuf[0] + lane * 8 + 4);
      float s[4] = {0.f, 0.f, 0.f, 0.f};
      fma8(wh0, a0, a1, s);
      float4 v = wredsum4(make_float4(s[0], s[1], s[2], s[3]));
      if (lane == 0) pput(&g_hp[0][0][r], cellup(v, b00, c0), 2u);
    }
    __syncthreads();  // WAR: S1(0) staging overwrites sBuf[0]

    // ---- Decoder main loop: 1 poll + 1 critical matvec per phase;
    //      all 128 producer blocks perfectly symmetric every phase. ----
    for (int t = 0; t < T; ++t) {
      const int pb = t & 1, ob = pb ^ 1;
      const unsigned wn = (unsigned)(t + 2);
      const unsigned wo = (unsigned)(t + 1);

      if (t >= 1) {  // S0: crit = M(LDS)@h2(t-1) + sOld0 + b0p
        W8 wh2 = ldw_g(p.dWhh + (size_t)8 * H * H, r, lane);  // prefetch (extra)
        stagev(g_hp[ob][2], wo, sBuf[bi]);
        W8 wm = ldw_lds(sM, w, lane);
        float4 h20 = *(const float4*)(sBuf[bi] + lane * 8);
        float4 h21 = *(const float4*)(sBuf[bi] + lane * 8 + 4);
        float s[4] = {sOld0[0], sOld0[1], sOld0[2], sOld0[3]};
        fma8(wm, h20, h21, s);
        float4 v = wredsum4(make_float4(s[0], s[1], s[2], s[3]));
        if (lane == 0) pput(&g_hp[pb][0][r], cellup(v, b0p, c0), wn);
        sOld2[0] = sOld2[1] = sOld2[2] = sOld2[3] = 0.f;
        fma8(wh2, h20, h21, sOld2);  // off-critical: for S2(t)
        bi ^= 1;
      }

      {  // S1: crit = dW1@h0(t) + sOld1; extra = Whh0@h0(t) -> sOld0 for S0(t+1)
        W8 wi  = ldw_g(p.dW1, r, lane);   // crit weights in flight during poll
        W8 wh0 = ldw_g(p.dWhh, r, lane);
        stagev(g_hp[pb][0], wn, sBuf[bi]);
        float4 a0 = *(const float4*)(sBuf[bi] + lane * 8);
        float4 a1 = *(const float4*)(sBuf[bi] + lane * 8 + 4);
        float s[4] = {sOld1[0], sOld1[1], sOld1[2], sOld1[3]};
        fma8(wi, a0, a1, s);
        float4 v = wredsum4(make_float4(s[0], s[1], s[2], s[3]));
        if (lane == 0) pput(&g_hp[pb][1][r], cellup(v, b1s, c1), wn);
        sOld0[0] = sOld0[1] = sOld0[2] = sOld0[3] = 0.f;
        fma8(wh0, a0, a1, sOld0);
        bi ^= 1;
      }
      {  // S2: crit = dW2@h1(t) + sOld2; extra = Whh1@h1(t) -> sOld1 for S1(t+1)
        W8 wi  = ldw_g(p.dW2, r, lane);
        W8 wh1 = ldw_g(p.dWhh + (size_t)4 * H * H, r, lane);
        stagev(g_hp[pb][1], wn, sBuf[bi]);
        float4 a0 = *(const float4*)(sBuf[bi] + lane * 8);
        float4 a1 = *(const float4*)(sBuf[bi] + lane * 8 + 4);
        float s[4] = {sOld2[0], sOld2[1], sOld2[2], sOld2[3]};
        fma8(wi, a0, a1, s);
        float4 v = wredsum4(make_float4(s[0], s[1], s[2], s[3]));
        if (lane == 0) {
          float hv = cellup(v, b2s, c2);
          pput(&g_hp[pb][2][r], hv, wn);   // main chain first
          pput(&g_hy[t][r], hv, wn);       // y-writer copy (step-unique slot)
        }
        sOld1[0] = sOld1[1] = sOld1[2] = sOld1[3] = 0.f;
        fma8(wh1, a0, a1, sOld1);
        bi ^= 1;
      }
    }
  }

  // ---- Exit: last block resets all tags so graph replays start clean ----
  __syncthreads();
  if (threadIdx.x == 0) {
    unsigned old = __hip_atomic_fetch_add(&g_exit, 1u, __ATOMIC_RELAXED, SCOPE_AGENT);
    s_last = (old == NB - 1) ? 1 : 0;
  }
  __syncthreads();
  if (s_last) {
    unsigned long long* z = &g_hp[0][0][0];
    for (int i = threadIdx.x; i < 2 * 3 * H; i += NT)
      __hip_atomic_store(z + i, 0ull, __ATOMIC_RELAXED, SCOPE_AGENT);
    unsigned long long* y = &g_hy[0][0];
    for (int i = threadIdx.x; i < T * H; i += NT)
      __hip_atomic_store(y + i, 0ull, __ATOMIC_RELAXED, SCOPE_AGENT);
    if (threadIdx.x == 0)
      __hip_atomic_store(&g_exit, 0u, __ATOMIC_RELAXED, SCOPE_AGENT);
  }
}

extern "C" void kernel_launch(void* const* d_in, const int* in_sizes, int n_in,
                              void* d_out, int out_size, void* d_ws, size_t ws_size,
                              hipStream_t stream) {
  P p;
  p.x    = (const float*)d_in[0];
  p.py   = (const float*)d_in[1];
  p.eW0  = (const float*)d_in[2];
  p.eW1  = (const float*)d_in[3];
  p.eW2  = (const float*)d_in[4];
  // d_in[5] enc_Whh: unused (encoder runs one step from h=0)
  p.ebih = (const float*)d_in[6];
  p.ebhh = (const float*)d_in[7];
  // d_in[8..10] attn_W/attn_b/v_W: unused (softmax over length-1 axis == 1)
  p.dW0  = (const float*)d_in[11];
  p.dW1  = (const float*)d_in[12];
  p.dW2  = (const float*)d_in[13];
  p.dWhh = (const float*)d_in[14];
  p.dbih = (const float*)d_in[15];
  p.dbhh = (const float*)d_in[16];
  p.outW = (const float*)d_in[17];
  p.outb = (const float*)d_in[18];
  p.out  = (float*)d_out;

  hipLaunchKernelGGL(k_flow, dim3(NB), dim3(NT), 0, stream, p);
}